// Round 11
// baseline (322.906 us; speedup 1.0000x reference)
//
#include <hip/hip_runtime.h>
#include <hip/hip_fp16.h>

#define NPTS 500000
#define NBINS 32768   // 32^3 Morton bins
#define NSUPER 8192   // 4 bins merged (2x2 in x,y)

// Planes stored fp16, pre-scaled by 1024 (exact pow2); final result * 1/1024.
#define PLANE_SCALE 1024.0f
#define INV_PLANE_SCALE 0.0009765625f

// ---------------------------------------------------------------------------
// Keys cubic conv weights, a = -0.75, taps at offsets [-1,0,1,2], t in [0,1)
// ---------------------------------------------------------------------------
__device__ __forceinline__ void cubic_w(float t, float w[4]) {
  const float a = -0.75f;
  const float t1 = t + 1.0f;
  w[0] = ((a * t1 - 5.0f * a) * t1 + 8.0f * a) * t1 - 4.0f * a;
  w[1] = ((a + 2.0f) * t - (a + 3.0f)) * t * t + 1.0f;
  const float u = 1.0f - t;
  w[2] = ((a + 2.0f) * u - (a + 3.0f)) * u * u + 1.0f;
  const float t2 = 2.0f - t;
  w[3] = ((a * t2 - 5.0f * a) * t2 + 8.0f * a) * t2 - 4.0f * a;
}

// ---------------------------------------------------------------------------
// Transpose (C,H,W) fp32 -> (H*W, C) fp16*1024, 3 planes batched on blockIdx.y
// ---------------------------------------------------------------------------
__global__ __launch_bounds__(256) void transpose_chw_hwc_f16(
    const float* __restrict__ p0, const float* __restrict__ p1,
    const float* __restrict__ p2, __half* __restrict__ dst, int HW) {
  __shared__ float lds[64][65];
  const float* src = (blockIdx.y == 0) ? p0 : ((blockIdx.y == 1) ? p1 : p2);
  __half* out = dst + (size_t)blockIdx.y * (size_t)HW * 64;
  const int pixBase = blockIdx.x * 64;
  const int tid = threadIdx.x;
  const int lane = tid & 63;
  const int quad = tid >> 6;
#pragma unroll
  for (int k = 0; k < 16; ++k) {
    const int c = k * 4 + quad;
    lds[c][lane] = src[(size_t)c * HW + pixBase + lane];
  }
  __syncthreads();
#pragma unroll
  for (int k = 0; k < 16; ++k) {
    const int pp = k * 4 + quad;
    out[(size_t)(pixBase + pp) * 64 + lane] =
        __float2half(lds[lane][pp] * PLANE_SCALE);
  }
}

// ---------------------------------------------------------------------------
// Morton binning helpers
// ---------------------------------------------------------------------------
__device__ __forceinline__ unsigned spread3(unsigned v) {
  return (v & 1u) | ((v & 2u) << 2) | ((v & 4u) << 4) | ((v & 8u) << 6) |
         ((v & 16u) << 8);
}

__device__ __forceinline__ unsigned compact3(unsigned v) {
  return (v & 1u) | ((v >> 2) & 2u) | ((v >> 4) & 4u) | ((v >> 6) & 8u) |
         ((v >> 8) & 16u);
}

__device__ __forceinline__ int bin_of(float cx, float cy, float cz) {
  int xq = (int)((cx + 1.0f) * 16.0f);
  int yq = (int)((cy + 1.0f) * 16.0f);
  int zq = (int)((cz + 1.0f) * 16.0f);
  xq = xq < 0 ? 0 : (xq > 31 ? 31 : xq);
  yq = yq < 0 ? 0 : (yq > 31 ? 31 : yq);
  zq = zq < 0 ? 0 : (zq > 31 ? 31 : zq);
  return (int)(spread3((unsigned)xq) | (spread3((unsigned)yq) << 1) |
               (spread3((unsigned)zq) << 2));
}

__global__ __launch_bounds__(256) void bin_count(
    const float* __restrict__ coords, int* __restrict__ counts) {
  const int pt = blockIdx.x * 256 + threadIdx.x;
  if (pt >= NPTS) return;
  const int b = bin_of(coords[pt * 3], coords[pt * 3 + 1], coords[pt * 3 + 2]);
  atomicAdd(&counts[b], 1);
}

__global__ __launch_bounds__(1024) void bin_scan(
    const int* __restrict__ counts, int* __restrict__ cursor) {
  __shared__ int lds[1024];
  const int t = threadIdx.x;
  const int base = t * 32;
  int s = 0;
#pragma unroll
  for (int i = 0; i < 32; ++i) s += counts[base + i];
  lds[t] = s;
  __syncthreads();
  int own = s;
  for (int off = 1; off < 1024; off <<= 1) {
    int v = (t >= off) ? lds[t - off] : 0;
    __syncthreads();
    lds[t] += v;
    __syncthreads();
  }
  int run = lds[t] - own;
#pragma unroll
  for (int i = 0; i < 32; ++i) {
    cursor[base + i] = run;
    run += counts[base + i];
  }
}

// ---------------------------------------------------------------------------
// Scatter fused with weight precompute. Per point, per scale, 32-B record:
// {wx01, wx23, wy01, wy23, wz01, wz23, relx*4|rely*4<<8|relz<<16, pt}
// rel are window-relative tap bases for the 2x2-merged superbin window.
// ---------------------------------------------------------------------------
__global__ __launch_bounds__(256) void bin_scatter_prep(
    const float* __restrict__ coords, int* __restrict__ cursor,
    uint4* __restrict__ wrec) {
  const int pt = blockIdx.x * 256 + threadIdx.x;
  if (pt >= NPTS) return;
  const float x = coords[pt * 3], y = coords[pt * 3 + 1],
              z = coords[pt * 3 + 2];
  const int b = bin_of(x, y, z);
  const int pos = atomicAdd(&cursor[b], 1);

  const int qx0 = ((int)compact3((unsigned)b)) & ~1;
  const int qy0 = ((int)compact3((unsigned)b >> 1)) & ~1;
  const int qz = (int)compact3((unsigned)b >> 2);
  const float vin[3] = {x, y, z};

#pragma unroll
  for (int s = 0; s < 3; ++s) {
    const int W = (s == 0) ? 256 : ((s == 1) ? 128 : 64);
    const float hw = 0.5f * (float)(W - 1);
    const int fb[3] = {(int)floorf((1.0f + (float)qx0 * 0.03125f) * hw),
                       (int)floorf((1.0f + (float)qy0 * 0.03125f) * hw),
                       (int)floorf((1.0f + (float)qz * 0.03125f) * hw)};
    uint wp[6];
    int rel[3];
#pragma unroll
    for (int a = 0; a < 3; ++a) {
      const float c = (vin[a] + 1.0f) * 0.5f;
      const float gx = (c + 1.0f) * 0.5f * (float)(W - 1);
      const float x0f = floorf(gx);
      float w[4];
      cubic_w(gx - x0f, w);
      int r = (int)x0f - fb[a];
      const int rmax = (a == 2) ? 4 : 12;
      r = r < 0 ? 0 : (r > rmax ? rmax : r);
      rel[a] = r;
      const __half2 lo = __halves2half2(__float2half(w[0]), __float2half(w[1]));
      const __half2 hi = __halves2half2(__float2half(w[2]), __float2half(w[3]));
      wp[a * 2] = *(const uint*)&lo;
      wp[a * 2 + 1] = *(const uint*)&hi;
    }
    uint4* dst = wrec + ((size_t)s * NPTS + pos) * 2;
    dst[0] = make_uint4(wp[0], wp[1], wp[2], wp[3]);
    dst[1] = make_uint4(
        wp[4], wp[5],
        (uint)(rel[0] * 4) | ((uint)(rel[1] * 4) << 8) | ((uint)rel[2] << 16),
        (uint)pt);
  }
}

// ---------------------------------------------------------------------------
// Superbin sampling: block per (superbin, scale, ch-half). 32 ch per block.
// LDS: 32 rows (XY 16y, YZ 8z, XZ 8z) x 16 cols x 4 cg uint4, LINEAR (32 KB).
// 8 lanes/point, lane i = tid&7 reads slots base+i (vA) and base+8+i (vB):
// each point's 8 lanes cover all 8 slot-groups mod 8 exactly once, so a
// 16-lane quarter-wave (2 points) hits every bank exactly 2x for ANY pair of
// relx values -> conflict-free by construction (2/bank is free, m136).
// Lane's columns are {cp, cp+2} where cp = (tid>>2)&1.
// ---------------------------------------------------------------------------
__global__ __launch_bounds__(256, 4) void sample_super(
    const uint4* __restrict__ wrec, const ushort* __restrict__ tp,
    const int* __restrict__ endc, float* __restrict__ out) {
  __shared__ uint4 win[2048];

  const int orig = blockIdx.x;
  const int sb = (orig & 7) * (NSUPER / 8) + (orig >> 3);
  const int b0 = sb * 4;  // 4 consecutive Morton bins = 2x2 in (x,y)
  const int start = (b0 == 0) ? 0 : endc[b0 - 1];
  const int end = endc[b0 + 3];
  if (start >= end) return;

  const int s = blockIdx.y;
  const int h = blockIdx.z;  // channel half: 0 or 1
  const int W = (s == 0) ? 256 : ((s == 1) ? 128 : 64);
  const size_t sbase = (s == 0) ? 0 : ((s == 1) ? 12582912 : 15728640);
  const size_t psz = (size_t)W * W * 64;
  const float hw = 0.5f * (float)(W - 1);

  const int qx0 = ((int)compact3((unsigned)b0)) & ~1;
  const int qy0 = ((int)compact3((unsigned)b0 >> 1)) & ~1;
  const int qz = (int)compact3((unsigned)b0 >> 2);
  const int wbx = (int)floorf((1.0f + (float)qx0 * 0.03125f) * hw) - 1;
  const int wby = (int)floorf((1.0f + (float)qy0 * 0.03125f) * hw) - 1;
  const int wbz = (int)floorf((1.0f + (float)qz * 0.03125f) * hw) - 1;

  const char* tpb = (const char*)(tp + sbase) + h * 64;  // 32-ch half
  const int tid = threadIdx.x;
  const int wave = tid >> 6;
  const int lane = tid & 63;
  const int px = lane >> 2;  // 0..15 pixel within row
  const int cgl = lane & 3;  // 0..3 channel group
#pragma unroll
  for (int k = 0; k < 8; ++k) {
    const int row = k * 4 + wave;  // 0..31
    int p, grow, cb;
    if (row < 16) {
      p = 0;
      grow = wby + row;
      cb = wbx;
    } else if (row < 24) {
      p = 1;
      grow = wbz + row - 16;
      cb = wby;
    } else {
      p = 2;
      grow = wbz + row - 24;
      cb = wbx;
    }
    grow = grow < 0 ? 0 : (grow > W - 1 ? W - 1 : grow);
    int gcol = cb + px;
    gcol = gcol < 0 ? 0 : (gcol > W - 1 ? W - 1 : gcol);
    const char* src = tpb + (size_t)p * psz * 2 +
                      ((size_t)grow * W + gcol) * 128 + cgl * 16;
#if __has_builtin(__builtin_amdgcn_global_load_lds)
    __builtin_amdgcn_global_load_lds((const uint*)src,
                                     (uint*)&win[row * 64], 16, 0, 0);
#else
    win[row * 64 + lane] = *reinterpret_cast<const uint4*>(src);
#endif
  }
  __syncthreads();

  const int lanegrp = tid >> 3;  // 32 point slots per block iteration
  const int i8 = tid & 7;        // lane's uint4 slot within point segment
  const int cg = tid & 3;        // channel group within half
  const int colpair = (tid >> 2) & 1;  // cols {0,2} or {1,3}

  for (int i0 = start; i0 < end; i0 += 32) {
    const int slot = i0 + lanegrp;
    if (slot >= end) break;
    const uint4 r0 = wrec[((size_t)s * NPTS + slot) * 2];
    const uint4 r1 = wrec[((size_t)s * NPTS + slot) * 2 + 1];
    const int pt = (int)r1.w;
    const int relx4 = (int)(r1.z & 255u);         // rel_x * 4
    const int rely4 = (int)((r1.z >> 8) & 255u);  // rel_y * 4
    const int relz = (int)((r1.z >> 16) & 255u);
    const int rely = rely4 >> 2;

    // broadcast weights
    const __half2 hx01 = *(const __half2*)&r0.x;
    const __half2 hx23 = *(const __half2*)&r0.y;
    const __half2 hy01 = *(const __half2*)&r0.z;
    const __half2 hy23 = *(const __half2*)&r0.w;
    const __half2 hz01 = *(const __half2*)&r1.x;
    const __half2 hz23 = *(const __half2*)&r1.y;
    __half2 wyb[4], wzb[4];
    wyb[0] = __half2half2(__low2half(hy01));
    wyb[1] = __half2half2(__high2half(hy01));
    wyb[2] = __half2half2(__low2half(hy23));
    wyb[3] = __half2half2(__high2half(hy23));
    wzb[0] = __half2half2(__low2half(hz01));
    wzb[1] = __half2half2(__high2half(hz01));
    wzb[2] = __half2half2(__low2half(hz23));
    wzb[3] = __half2half2(__high2half(hz23));
    // per-lane column weights: cols {colpair, colpair+2}
    const __half2 cxA =
        __half2half2(colpair ? __high2half(hx01) : __low2half(hx01));
    const __half2 cxB =
        __half2half2(colpair ? __high2half(hx23) : __low2half(hx23));
    const __half2 cyA =
        __half2half2(colpair ? __high2half(hy01) : __low2half(hy01));
    const __half2 cyB =
        __half2half2(colpair ? __high2half(hy23) : __low2half(hy23));

    // LDS bases (uint4 units); vA = base + j*64, vB = +8
    const int bXY = rely * 64 + relx4 + i8;
    const int bYZ = 1024 + relz * 64 + rely4 + i8;
    const int bXZ = 1536 + relz * 64 + relx4 + i8;

    __half2 acc0 = __float2half2_rn(0.0f), acc1 = acc0, acc2 = acc0,
            acc3 = acc0;

#define PLANE(BASE, CWA, CWB, RW)                                   \
  _Pragma("unroll") for (int j = 0; j < 4; ++j) {                   \
    const __half2 mA = __hmul2(CWA, RW[j]);                         \
    const __half2 mB = __hmul2(CWB, RW[j]);                         \
    const uint4 vA = win[(BASE) + j * 64];                          \
    const uint4 vB = win[(BASE) + j * 64 + 8];                      \
    acc0 = __hfma2(mA, *(const __half2*)&vA.x, acc0);               \
    acc1 = __hfma2(mA, *(const __half2*)&vA.y, acc1);               \
    acc2 = __hfma2(mA, *(const __half2*)&vA.z, acc2);               \
    acc3 = __hfma2(mA, *(const __half2*)&vA.w, acc3);               \
    acc0 = __hfma2(mB, *(const __half2*)&vB.x, acc0);               \
    acc1 = __hfma2(mB, *(const __half2*)&vB.y, acc1);               \
    acc2 = __hfma2(mB, *(const __half2*)&vB.z, acc2);               \
    acc3 = __hfma2(mB, *(const __half2*)&vB.w, acc3);               \
  }

    PLANE(bXY, cxA, cxB, wyb);  // XY: row=y, col=x
    PLANE(bYZ, cyA, cyB, wzb);  // YZ: row=z, col=y
    PLANE(bXZ, cxA, cxB, wzb);  // XZ: row=z, col=x
#undef PLANE

    // butterfly over the colpair bit (tid^4): cols {0,2}+{1,3} = all 4
    {
      uint u0 = *(const uint*)&acc0, u1 = *(const uint*)&acc1,
           u2 = *(const uint*)&acc2, u3 = *(const uint*)&acc3;
      const uint p0 = __shfl_xor((int)u0, 4, 64);
      const uint p1 = __shfl_xor((int)u1, 4, 64);
      const uint p2 = __shfl_xor((int)u2, 4, 64);
      const uint p3 = __shfl_xor((int)u3, 4, 64);
      acc0 = __hadd2(acc0, *(const __half2*)&p0);
      acc1 = __hadd2(acc1, *(const __half2*)&p1);
      acc2 = __hadd2(acc2, *(const __half2*)&p2);
      acc3 = __hadd2(acc3, *(const __half2*)&p3);
    }

    // lane writes 4 of its 8 channels, selected by colpair -> 128 B/point
    const __half2 o0 = colpair ? acc2 : acc0;
    const __half2 o1 = colpair ? acc3 : acc1;
    const float2 f0 = __half22float2(o0);
    const float2 f1 = __half22float2(o1);
    *reinterpret_cast<float4*>(out + (size_t)pt * 192 + s * 64 + h * 32 +
                               cg * 8 + colpair * 4) =
        make_float4(f0.x * INV_PLANE_SCALE, f0.y * INV_PLANE_SCALE,
                    f1.x * INV_PLANE_SCALE, f1.y * INV_PLANE_SCALE);
  }
}

// ---------------------------------------------------------------------------
// Fallback: fp32 direct from (C,H,W) if workspace too small.
// ---------------------------------------------------------------------------
__device__ __forceinline__ void sample_acc_chw(const float* __restrict__ plane,
                                               int W, float gx, float gy,
                                               int cg, float4& acc) {
  const float x = (gx + 1.0f) * 0.5f * (float)(W - 1);
  const float y = (gy + 1.0f) * 0.5f * (float)(W - 1);
  const float x0f = floorf(x), y0f = floorf(y);
  float wx[4], wy[4];
  cubic_w(x - x0f, wx);
  cubic_w(y - y0f, wy);
  const int x0 = (int)x0f, y0 = (int)y0f;
  int ix[4], iy[4];
#pragma unroll
  for (int i = 0; i < 4; ++i) {
    int xi = x0 - 1 + i;
    ix[i] = xi < 0 ? 0 : (xi > W - 1 ? W - 1 : xi);
    int yi = y0 - 1 + i;
    iy[i] = yi < 0 ? 0 : (yi > W - 1 ? W - 1 : yi);
  }
  const size_t HW = (size_t)W * W;
  float r[4] = {acc.x, acc.y, acc.z, acc.w};
#pragma unroll
  for (int cc = 0; cc < 4; ++cc) {
    const float* pc = plane + (size_t)(cg * 4 + cc) * HW;
    float a = 0.f;
#pragma unroll
    for (int j = 0; j < 4; ++j) {
      const float* rb = pc + (size_t)iy[j] * W;
      float row = 0.f;
#pragma unroll
      for (int i = 0; i < 4; ++i) row += wx[i] * rb[ix[i]];
      a += wy[j] * row;
    }
    r[cc] += a;
  }
  acc = make_float4(r[0], r[1], r[2], r[3]);
}

__global__ __launch_bounds__(256) void sample_fallback(
    const float* __restrict__ coords, const float* __restrict__ px0,
    const float* __restrict__ py0, const float* __restrict__ pz0,
    const float* __restrict__ px1, const float* __restrict__ py1,
    const float* __restrict__ pz1, const float* __restrict__ px2,
    const float* __restrict__ py2, const float* __restrict__ pz2,
    float* __restrict__ out) {
  const int t = blockIdx.x * 256 + threadIdx.x;
  const int pt = t >> 4;
  const int cg = t & 15;
  if (pt >= NPTS) return;
  const float cx = (coords[pt * 3 + 0] + 1.0f) * 0.5f;
  const float cy = (coords[pt * 3 + 1] + 1.0f) * 0.5f;
  const float cz = (coords[pt * 3 + 2] + 1.0f) * 0.5f;
  const float* xs[3] = {px0, px1, px2};
  const float* ys[3] = {py0, py1, py2};
  const float* zs[3] = {pz0, pz1, pz2};
  const int sw[3] = {256, 128, 64};
  float* optr = out + (size_t)pt * 192 + cg * 4;
#pragma unroll
  for (int s = 0; s < 3; ++s) {
    const int W = sw[s];
    float4 acc = make_float4(0.f, 0.f, 0.f, 0.f);
    sample_acc_chw(xs[s], W, cx, cy, cg, acc);
    sample_acc_chw(ys[s], W, cy, cz, cg, acc);
    sample_acc_chw(zs[s], W, cx, cz, cg, acc);
    *reinterpret_cast<float4*>(optr + s * 64) = acc;
  }
}

// ---------------------------------------------------------------------------
extern "C" void kernel_launch(void* const* d_in, const int* in_sizes, int n_in,
                              void* d_out, int out_size, void* d_ws,
                              size_t ws_size, hipStream_t stream) {
  const float* coords = (const float*)d_in[0];
  const float* px0 = (const float*)d_in[1];
  const float* py0 = (const float*)d_in[2];
  const float* pz0 = (const float*)d_in[3];
  const float* px1 = (const float*)d_in[4];
  const float* py1 = (const float*)d_in[5];
  const float* pz1 = (const float*)d_in[6];
  const float* px2 = (const float*)d_in[7];
  const float* py2 = (const float*)d_in[8];
  const float* pz2 = (const float*)d_in[9];
  float* out = (float*)d_out;

  // ws layout (bytes): f16 planes, counts, end-cursor, weight records
  const size_t TP_BYTES = 33030144;
  const size_t CNT_OFF = TP_BYTES;           // 131072 B
  const size_t CUR_OFF = CNT_OFF + 131072;   // 131072 B
  const size_t REC_OFF = CUR_OFF + 131072;   // 48,000,000 B
  const size_t NEEDED = REC_OFF + (size_t)NPTS * 3 * 32;

  if (ws_size >= NEEDED) {
    __half* tp = (__half*)d_ws;
    int* counts = (int*)((char*)d_ws + CNT_OFF);
    int* cursor = (int*)((char*)d_ws + CUR_OFF);
    uint4* wrec = (uint4*)((char*)d_ws + REC_OFF);

    transpose_chw_hwc_f16<<<dim3(65536 / 64, 3), 256, 0, stream>>>(
        px0, py0, pz0, tp + 0, 65536);
    transpose_chw_hwc_f16<<<dim3(16384 / 64, 3), 256, 0, stream>>>(
        px1, py1, pz1, tp + 12582912, 16384);
    transpose_chw_hwc_f16<<<dim3(4096 / 64, 3), 256, 0, stream>>>(
        px2, py2, pz2, tp + 15728640, 4096);

    hipMemsetAsync(counts, 0, NBINS * sizeof(int), stream);
    const int pblocks = (NPTS + 255) / 256;
    bin_count<<<pblocks, 256, 0, stream>>>(coords, counts);
    bin_scan<<<1, 1024, 0, stream>>>(counts, cursor);
    bin_scatter_prep<<<pblocks, 256, 0, stream>>>(coords, cursor, wrec);
    // cursor[b] now == end offset of bin b

    sample_super<<<dim3(NSUPER, 3, 2), 256, 0, stream>>>(
        wrec, (const ushort*)tp, cursor, out);
  } else {
    const int sample_blocks = (NPTS * 16 + 255) / 256;
    sample_fallback<<<sample_blocks, 256, 0, stream>>>(
        coords, px0, py0, pz0, px1, py1, pz1, px2, py2, pz2, out);
  }
}

// Round 12
// 284.982 us; speedup vs baseline: 1.1331x; 1.1331x over previous
//
#include <hip/hip_runtime.h>
#include <hip/hip_fp16.h>

#define NPTS 500000
#define NBINS 32768  // 32^3 Morton bins

// Planes stored fp16, pre-scaled by 1024 (exact pow2); final result * 1/1024.
#define PLANE_SCALE 1024.0f
#define INV_PLANE_SCALE 0.0009765625f

// ---------------------------------------------------------------------------
// Keys cubic conv weights, a = -0.75, taps at offsets [-1,0,1,2], t in [0,1)
// ---------------------------------------------------------------------------
__device__ __forceinline__ void cubic_w(float t, float w[4]) {
  const float a = -0.75f;
  const float t1 = t + 1.0f;
  w[0] = ((a * t1 - 5.0f * a) * t1 + 8.0f * a) * t1 - 4.0f * a;
  w[1] = ((a + 2.0f) * t - (a + 3.0f)) * t * t + 1.0f;
  const float u = 1.0f - t;
  w[2] = ((a + 2.0f) * u - (a + 3.0f)) * u * u + 1.0f;
  const float t2 = 2.0f - t;
  w[3] = ((a * t2 - 5.0f * a) * t2 + 8.0f * a) * t2 - 4.0f * a;
}

// ---------------------------------------------------------------------------
// Transpose (C,H,W) fp32 -> (H*W, C) fp16*1024, 3 planes batched on blockIdx.y
// ---------------------------------------------------------------------------
__global__ __launch_bounds__(256) void transpose_chw_hwc_f16(
    const float* __restrict__ p0, const float* __restrict__ p1,
    const float* __restrict__ p2, __half* __restrict__ dst, int HW) {
  __shared__ float lds[64][65];
  const float* src = (blockIdx.y == 0) ? p0 : ((blockIdx.y == 1) ? p1 : p2);
  __half* out = dst + (size_t)blockIdx.y * (size_t)HW * 64;
  const int pixBase = blockIdx.x * 64;
  const int tid = threadIdx.x;
  const int lane = tid & 63;
  const int quad = tid >> 6;
#pragma unroll
  for (int k = 0; k < 16; ++k) {
    const int c = k * 4 + quad;
    lds[c][lane] = src[(size_t)c * HW + pixBase + lane];
  }
  __syncthreads();
#pragma unroll
  for (int k = 0; k < 16; ++k) {
    const int pp = k * 4 + quad;
    out[(size_t)(pixBase + pp) * 64 + lane] =
        __float2half(lds[lane][pp] * PLANE_SCALE);
  }
}

// ---------------------------------------------------------------------------
// Morton binning helpers
// ---------------------------------------------------------------------------
__device__ __forceinline__ unsigned spread3(unsigned v) {
  return (v & 1u) | ((v & 2u) << 2) | ((v & 4u) << 4) | ((v & 8u) << 6) |
         ((v & 16u) << 8);
}

__device__ __forceinline__ unsigned compact3(unsigned v) {
  return (v & 1u) | ((v >> 2) & 2u) | ((v >> 4) & 4u) | ((v >> 6) & 8u) |
         ((v >> 8) & 16u);
}

__device__ __forceinline__ int bin_of(float cx, float cy, float cz) {
  int xq = (int)((cx + 1.0f) * 16.0f);
  int yq = (int)((cy + 1.0f) * 16.0f);
  int zq = (int)((cz + 1.0f) * 16.0f);
  xq = xq < 0 ? 0 : (xq > 31 ? 31 : xq);
  yq = yq < 0 ? 0 : (yq > 31 ? 31 : yq);
  zq = zq < 0 ? 0 : (zq > 31 ? 31 : zq);
  return (int)(spread3((unsigned)xq) | (spread3((unsigned)yq) << 1) |
               (spread3((unsigned)zq) << 2));
}

__global__ __launch_bounds__(256) void bin_count(
    const float* __restrict__ coords, int* __restrict__ counts) {
  const int pt = blockIdx.x * 256 + threadIdx.x;
  if (pt >= NPTS) return;
  const int b = bin_of(coords[pt * 3], coords[pt * 3 + 1], coords[pt * 3 + 2]);
  atomicAdd(&counts[b], 1);
}

__global__ __launch_bounds__(1024) void bin_scan(
    const int* __restrict__ counts, int* __restrict__ cursor) {
  __shared__ int lds[1024];
  const int t = threadIdx.x;
  const int base = t * 32;
  int s = 0;
#pragma unroll
  for (int i = 0; i < 32; ++i) s += counts[base + i];
  lds[t] = s;
  __syncthreads();
  int own = s;
  for (int off = 1; off < 1024; off <<= 1) {
    int v = (t >= off) ? lds[t - off] : 0;
    __syncthreads();
    lds[t] += v;
    __syncthreads();
  }
  int run = lds[t] - own;
#pragma unroll
  for (int i = 0; i < 32; ++i) {
    cursor[base + i] = run;
    run += counts[base + i];
  }
}

// ---------------------------------------------------------------------------
// Scatter fused with weight precompute. Per point, per scale, 32-B record:
// {wx01, wx23, wy01, wy23, wz01, wz23, relx*4|rely*4<<8|relz<<16, pt}
// rel are window-relative tap bases for the per-scale merged superbin window.
// Merge factors: scale0 m=4 (2x2x1), scales 1-2 m=16 (4x2x2 in x,y,z).
// Window rows: XY 12 (rel_y<=8), YZ 8 (rel_z<=4), XZ 8; cols 16 (rel_x<=12).
// ---------------------------------------------------------------------------
__global__ __launch_bounds__(256) void bin_scatter_prep(
    const float* __restrict__ coords, int* __restrict__ cursor,
    uint4* __restrict__ wrec) {
  const int pt = blockIdx.x * 256 + threadIdx.x;
  if (pt >= NPTS) return;
  const float x = coords[pt * 3], y = coords[pt * 3 + 1],
              z = coords[pt * 3 + 2];
  const int b = bin_of(x, y, z);
  const int pos = atomicAdd(&cursor[b], 1);

  const float vin[3] = {x, y, z};

#pragma unroll
  for (int s = 0; s < 3; ++s) {
    const int W = (s == 0) ? 256 : ((s == 1) ? 128 : 64);
    const float hw = 0.5f * (float)(W - 1);
    const int msk = (s == 0) ? 3 : 15;
    const int bm = b & ~msk;
    const int q0[3] = {(int)compact3((unsigned)bm),
                       (int)compact3((unsigned)bm >> 1),
                       (int)compact3((unsigned)bm >> 2)};
    uint wp[6];
    int rel[3];
#pragma unroll
    for (int a = 0; a < 3; ++a) {
      const float c = (vin[a] + 1.0f) * 0.5f;
      const float gx = (c + 1.0f) * 0.5f * (float)(W - 1);
      const float x0f = floorf(gx);
      float w[4];
      cubic_w(gx - x0f, w);
      const int fb = (int)floorf((1.0f + (float)q0[a] * 0.03125f) * hw);
      int r = (int)x0f - fb;
      const int rmax = (a == 0) ? 12 : ((a == 1) ? 8 : 4);
      r = r < 0 ? 0 : (r > rmax ? rmax : r);
      rel[a] = r;
      const __half2 lo = __halves2half2(__float2half(w[0]), __float2half(w[1]));
      const __half2 hi = __halves2half2(__float2half(w[2]), __float2half(w[3]));
      wp[a * 2] = *(const uint*)&lo;
      wp[a * 2 + 1] = *(const uint*)&hi;
    }
    uint4* dst = wrec + ((size_t)s * NPTS + pos) * 2;
    dst[0] = make_uint4(wp[0], wp[1], wp[2], wp[3]);
    dst[1] = make_uint4(
        wp[4], wp[5],
        (uint)(rel[0] * 4) | ((uint)(rel[1] * 4) << 8) | ((uint)rel[2] << 16),
        (uint)pt);
  }
}

// ---------------------------------------------------------------------------
// Superbin sampling: block per (superbin, scale, ch-half). 32 ch per block.
// LDS: 28 rows (XY 12y, YZ 8z, XZ 8z) x 16 cols x 4 cg uint4 = 28 KB, linear.
// Per-scale merge: scale0 m=4 -> 8192 superbins; scales 1-2 m=16 -> 2048.
// 8 lanes/point; lane i reads slots base+i and base+8+i (row-covering).
// ---------------------------------------------------------------------------
__global__ __launch_bounds__(256, 5) void sample_super(
    const uint4* __restrict__ wrec, const ushort* __restrict__ tp,
    const int* __restrict__ endc, float* __restrict__ out) {
  __shared__ uint4 win[1792];  // 28 rows x 64 uint4 = 28 KB

  const int s = blockIdx.y;
  const int NSUP = (s == 0) ? 8192 : 2048;
  const int m = (s == 0) ? 4 : 16;
  const int orig = blockIdx.x;
  if (orig >= NSUP) return;
  const int sb = (orig & 7) * (NSUP / 8) + (orig >> 3);
  const int b0 = sb * m;
  const int start = (b0 == 0) ? 0 : endc[b0 - 1];
  const int end = endc[b0 + m - 1];
  if (start >= end) return;

  const int h = blockIdx.z;  // channel half: 0 or 1
  const int W = (s == 0) ? 256 : ((s == 1) ? 128 : 64);
  const size_t sbase = (s == 0) ? 0 : ((s == 1) ? 12582912 : 15728640);
  const size_t psz = (size_t)W * W * 64;
  const float hw = 0.5f * (float)(W - 1);

  // b0 is a multiple of m -> merged low bits of qx/qy/qz are already zero
  const int qx0 = (int)compact3((unsigned)b0);
  const int qy0 = (int)compact3((unsigned)b0 >> 1);
  const int qz0 = (int)compact3((unsigned)b0 >> 2);
  const int wbx = (int)floorf((1.0f + (float)qx0 * 0.03125f) * hw) - 1;
  const int wby = (int)floorf((1.0f + (float)qy0 * 0.03125f) * hw) - 1;
  const int wbz = (int)floorf((1.0f + (float)qz0 * 0.03125f) * hw) - 1;

  const char* tpb = (const char*)(tp + sbase) + h * 64;  // 32-ch half
  const int tid = threadIdx.x;
  const int wave = tid >> 6;
  const int lane = tid & 63;
  const int px = lane >> 2;  // 0..15 pixel within row
  const int cgl = lane & 3;  // 0..3 channel group
#pragma unroll
  for (int k = 0; k < 7; ++k) {
    const int row = k * 4 + wave;  // 0..27
    int p, grow, cb;
    if (row < 12) {  // XY rows (y)
      p = 0;
      grow = wby + row;
      cb = wbx;
    } else if (row < 20) {  // YZ rows (z)
      p = 1;
      grow = wbz + row - 12;
      cb = wby;
    } else {  // XZ rows (z)
      p = 2;
      grow = wbz + row - 20;
      cb = wbx;
    }
    grow = grow < 0 ? 0 : (grow > W - 1 ? W - 1 : grow);
    int gcol = cb + px;
    gcol = gcol < 0 ? 0 : (gcol > W - 1 ? W - 1 : gcol);
    const char* src = tpb + (size_t)p * psz * 2 +
                      ((size_t)grow * W + gcol) * 128 + cgl * 16;
#if __has_builtin(__builtin_amdgcn_global_load_lds)
    __builtin_amdgcn_global_load_lds((const uint*)src,
                                     (uint*)&win[row * 64], 16, 0, 0);
#else
    win[row * 64 + lane] = *reinterpret_cast<const uint4*>(src);
#endif
  }
  __syncthreads();

  const int lanegrp = tid >> 3;  // 32 point slots per block iteration
  const int i8 = tid & 7;        // lane's uint4 slot within point segment
  const int cg = tid & 3;        // channel group within half
  const int colpair = (tid >> 2) & 1;  // cols {0,2} or {1,3}

  for (int i0 = start; i0 < end; i0 += 32) {
    const int slot = i0 + lanegrp;
    if (slot >= end) break;
    const uint4 r0 = wrec[((size_t)s * NPTS + slot) * 2];
    const uint4 r1 = wrec[((size_t)s * NPTS + slot) * 2 + 1];
    const int pt = (int)r1.w;
    const int relx4 = (int)(r1.z & 255u);         // rel_x * 4
    const int rely4 = (int)((r1.z >> 8) & 255u);  // rel_y * 4
    const int relz = (int)((r1.z >> 16) & 255u);
    const int rely = rely4 >> 2;

    // broadcast weights
    const __half2 hx01 = *(const __half2*)&r0.x;
    const __half2 hx23 = *(const __half2*)&r0.y;
    const __half2 hy01 = *(const __half2*)&r0.z;
    const __half2 hy23 = *(const __half2*)&r0.w;
    const __half2 hz01 = *(const __half2*)&r1.x;
    const __half2 hz23 = *(const __half2*)&r1.y;
    __half2 wyb[4], wzb[4];
    wyb[0] = __half2half2(__low2half(hy01));
    wyb[1] = __half2half2(__high2half(hy01));
    wyb[2] = __half2half2(__low2half(hy23));
    wyb[3] = __half2half2(__high2half(hy23));
    wzb[0] = __half2half2(__low2half(hz01));
    wzb[1] = __half2half2(__high2half(hz01));
    wzb[2] = __half2half2(__low2half(hz23));
    wzb[3] = __half2half2(__high2half(hz23));
    // per-lane column weights: cols {colpair, colpair+2}
    const __half2 cxA =
        __half2half2(colpair ? __high2half(hx01) : __low2half(hx01));
    const __half2 cxB =
        __half2half2(colpair ? __high2half(hx23) : __low2half(hx23));
    const __half2 cyA =
        __half2half2(colpair ? __high2half(hy01) : __low2half(hy01));
    const __half2 cyB =
        __half2half2(colpair ? __high2half(hy23) : __low2half(hy23));

    // LDS bases (uint4 units); vA = base + j*64, vB = +8
    const int bXY = rely * 64 + relx4 + i8;
    const int bYZ = 768 + relz * 64 + rely4 + i8;   // 12*64
    const int bXZ = 1280 + relz * 64 + relx4 + i8;  // 20*64

    __half2 acc0 = __float2half2_rn(0.0f), acc1 = acc0, acc2 = acc0,
            acc3 = acc0;

#define PLANE(BASE, CWA, CWB, RW)                                   \
  _Pragma("unroll") for (int j = 0; j < 4; ++j) {                   \
    const __half2 mA = __hmul2(CWA, RW[j]);                         \
    const __half2 mB = __hmul2(CWB, RW[j]);                         \
    const uint4 vA = win[(BASE) + j * 64];                          \
    const uint4 vB = win[(BASE) + j * 64 + 8];                      \
    acc0 = __hfma2(mA, *(const __half2*)&vA.x, acc0);               \
    acc1 = __hfma2(mA, *(const __half2*)&vA.y, acc1);               \
    acc2 = __hfma2(mA, *(const __half2*)&vA.z, acc2);               \
    acc3 = __hfma2(mA, *(const __half2*)&vA.w, acc3);               \
    acc0 = __hfma2(mB, *(const __half2*)&vB.x, acc0);               \
    acc1 = __hfma2(mB, *(const __half2*)&vB.y, acc1);               \
    acc2 = __hfma2(mB, *(const __half2*)&vB.z, acc2);               \
    acc3 = __hfma2(mB, *(const __half2*)&vB.w, acc3);               \
  }

    PLANE(bXY, cxA, cxB, wyb);  // XY: row=y, col=x
    PLANE(bYZ, cyA, cyB, wzb);  // YZ: row=z, col=y
    PLANE(bXZ, cxA, cxB, wzb);  // XZ: row=z, col=x
#undef PLANE

    // butterfly over the colpair bit (tid^4): cols {0,2}+{1,3} = all 4
    {
      uint u0 = *(const uint*)&acc0, u1 = *(const uint*)&acc1,
           u2 = *(const uint*)&acc2, u3 = *(const uint*)&acc3;
      const uint p0 = __shfl_xor((int)u0, 4, 64);
      const uint p1 = __shfl_xor((int)u1, 4, 64);
      const uint p2 = __shfl_xor((int)u2, 4, 64);
      const uint p3 = __shfl_xor((int)u3, 4, 64);
      acc0 = __hadd2(acc0, *(const __half2*)&p0);
      acc1 = __hadd2(acc1, *(const __half2*)&p1);
      acc2 = __hadd2(acc2, *(const __half2*)&p2);
      acc3 = __hadd2(acc3, *(const __half2*)&p3);
    }

    // lane writes 4 of its 8 channels, selected by colpair -> 128 B/point
    const __half2 o0 = colpair ? acc2 : acc0;
    const __half2 o1 = colpair ? acc3 : acc1;
    const float2 f0 = __half22float2(o0);
    const float2 f1 = __half22float2(o1);
    *reinterpret_cast<float4*>(out + (size_t)pt * 192 + s * 64 + h * 32 +
                               cg * 8 + colpair * 4) =
        make_float4(f0.x * INV_PLANE_SCALE, f0.y * INV_PLANE_SCALE,
                    f1.x * INV_PLANE_SCALE, f1.y * INV_PLANE_SCALE);
  }
}

// ---------------------------------------------------------------------------
// Fallback: fp32 direct from (C,H,W) if workspace too small.
// ---------------------------------------------------------------------------
__device__ __forceinline__ void sample_acc_chw(const float* __restrict__ plane,
                                               int W, float gx, float gy,
                                               int cg, float4& acc) {
  const float x = (gx + 1.0f) * 0.5f * (float)(W - 1);
  const float y = (gy + 1.0f) * 0.5f * (float)(W - 1);
  const float x0f = floorf(x), y0f = floorf(y);
  float wx[4], wy[4];
  cubic_w(x - x0f, wx);
  cubic_w(y - y0f, wy);
  const int x0 = (int)x0f, y0 = (int)y0f;
  int ix[4], iy[4];
#pragma unroll
  for (int i = 0; i < 4; ++i) {
    int xi = x0 - 1 + i;
    ix[i] = xi < 0 ? 0 : (xi > W - 1 ? W - 1 : xi);
    int yi = y0 - 1 + i;
    iy[i] = yi < 0 ? 0 : (yi > W - 1 ? W - 1 : yi);
  }
  const size_t HW = (size_t)W * W;
  float r[4] = {acc.x, acc.y, acc.z, acc.w};
#pragma unroll
  for (int cc = 0; cc < 4; ++cc) {
    const float* pc = plane + (size_t)(cg * 4 + cc) * HW;
    float a = 0.f;
#pragma unroll
    for (int j = 0; j < 4; ++j) {
      const float* rb = pc + (size_t)iy[j] * W;
      float row = 0.f;
#pragma unroll
      for (int i = 0; i < 4; ++i) row += wx[i] * rb[ix[i]];
      a += wy[j] * row;
    }
    r[cc] += a;
  }
  acc = make_float4(r[0], r[1], r[2], r[3]);
}

__global__ __launch_bounds__(256) void sample_fallback(
    const float* __restrict__ coords, const float* __restrict__ px0,
    const float* __restrict__ py0, const float* __restrict__ pz0,
    const float* __restrict__ px1, const float* __restrict__ py1,
    const float* __restrict__ pz1, const float* __restrict__ px2,
    const float* __restrict__ py2, const float* __restrict__ pz2,
    float* __restrict__ out) {
  const int t = blockIdx.x * 256 + threadIdx.x;
  const int pt = t >> 4;
  const int cg = t & 15;
  if (pt >= NPTS) return;
  const float cx = (coords[pt * 3 + 0] + 1.0f) * 0.5f;
  const float cy = (coords[pt * 3 + 1] + 1.0f) * 0.5f;
  const float cz = (coords[pt * 3 + 2] + 1.0f) * 0.5f;
  const float* xs[3] = {px0, px1, px2};
  const float* ys[3] = {py0, py1, py2};
  const float* zs[3] = {pz0, pz1, pz2};
  const int sw[3] = {256, 128, 64};
  float* optr = out + (size_t)pt * 192 + cg * 4;
#pragma unroll
  for (int s = 0; s < 3; ++s) {
    const int W = sw[s];
    float4 acc = make_float4(0.f, 0.f, 0.f, 0.f);
    sample_acc_chw(xs[s], W, cx, cy, cg, acc);
    sample_acc_chw(ys[s], W, cy, cz, cg, acc);
    sample_acc_chw(zs[s], W, cx, cz, cg, acc);
    *reinterpret_cast<float4*>(optr + s * 64) = acc;
  }
}

// ---------------------------------------------------------------------------
extern "C" void kernel_launch(void* const* d_in, const int* in_sizes, int n_in,
                              void* d_out, int out_size, void* d_ws,
                              size_t ws_size, hipStream_t stream) {
  const float* coords = (const float*)d_in[0];
  const float* px0 = (const float*)d_in[1];
  const float* py0 = (const float*)d_in[2];
  const float* pz0 = (const float*)d_in[3];
  const float* px1 = (const float*)d_in[4];
  const float* py1 = (const float*)d_in[5];
  const float* pz1 = (const float*)d_in[6];
  const float* px2 = (const float*)d_in[7];
  const float* py2 = (const float*)d_in[8];
  const float* pz2 = (const float*)d_in[9];
  float* out = (float*)d_out;

  // ws layout (bytes): f16 planes, counts, end-cursor, weight records
  const size_t TP_BYTES = 33030144;
  const size_t CNT_OFF = TP_BYTES;           // 131072 B
  const size_t CUR_OFF = CNT_OFF + 131072;   // 131072 B
  const size_t REC_OFF = CUR_OFF + 131072;   // 48,000,000 B
  const size_t NEEDED = REC_OFF + (size_t)NPTS * 3 * 32;

  if (ws_size >= NEEDED) {
    __half* tp = (__half*)d_ws;
    int* counts = (int*)((char*)d_ws + CNT_OFF);
    int* cursor = (int*)((char*)d_ws + CUR_OFF);
    uint4* wrec = (uint4*)((char*)d_ws + REC_OFF);

    transpose_chw_hwc_f16<<<dim3(65536 / 64, 3), 256, 0, stream>>>(
        px0, py0, pz0, tp + 0, 65536);
    transpose_chw_hwc_f16<<<dim3(16384 / 64, 3), 256, 0, stream>>>(
        px1, py1, pz1, tp + 12582912, 16384);
    transpose_chw_hwc_f16<<<dim3(4096 / 64, 3), 256, 0, stream>>>(
        px2, py2, pz2, tp + 15728640, 4096);

    hipMemsetAsync(counts, 0, NBINS * sizeof(int), stream);
    const int pblocks = (NPTS + 255) / 256;
    bin_count<<<pblocks, 256, 0, stream>>>(coords, counts);
    bin_scan<<<1, 1024, 0, stream>>>(counts, cursor);
    bin_scatter_prep<<<pblocks, 256, 0, stream>>>(coords, cursor, wrec);
    // cursor[b] now == end offset of bin b

    sample_super<<<dim3(8192, 3, 2), 256, 0, stream>>>(
        wrec, (const ushort*)tp, cursor, out);
  } else {
    const int sample_blocks = (NPTS * 16 + 255) / 256;
    sample_fallback<<<sample_blocks, 256, 0, stream>>>(
        coords, px0, py0, pz0, px1, py1, pz1, px2, py2, pz2, out);
  }
}

// Round 13
// 269.564 us; speedup vs baseline: 1.1979x; 1.0572x over previous
//
#include <hip/hip_runtime.h>
#include <hip/hip_fp16.h>

#define NPTS 500000
#define NBINS 32768  // 32^3 Morton bins

// Planes stored fp16, pre-scaled by 1024 (exact pow2); final result * 1/1024.
#define PLANE_SCALE 1024.0f
#define INV_PLANE_SCALE 0.0009765625f

// ---------------------------------------------------------------------------
// Keys cubic conv weights, a = -0.75, taps at offsets [-1,0,1,2], t in [0,1)
// ---------------------------------------------------------------------------
__device__ __forceinline__ void cubic_w(float t, float w[4]) {
  const float a = -0.75f;
  const float t1 = t + 1.0f;
  w[0] = ((a * t1 - 5.0f * a) * t1 + 8.0f * a) * t1 - 4.0f * a;
  w[1] = ((a + 2.0f) * t - (a + 3.0f)) * t * t + 1.0f;
  const float u = 1.0f - t;
  w[2] = ((a + 2.0f) * u - (a + 3.0f)) * u * u + 1.0f;
  const float t2 = 2.0f - t;
  w[3] = ((a * t2 - 5.0f * a) * t2 + 8.0f * a) * t2 - 4.0f * a;
}

// ---------------------------------------------------------------------------
// Morton binning helpers
// ---------------------------------------------------------------------------
__device__ __forceinline__ unsigned spread3(unsigned v) {
  return (v & 1u) | ((v & 2u) << 2) | ((v & 4u) << 4) | ((v & 8u) << 6) |
         ((v & 16u) << 8);
}

__device__ __forceinline__ unsigned compact3(unsigned v) {
  return (v & 1u) | ((v >> 2) & 2u) | ((v >> 4) & 4u) | ((v >> 6) & 8u) |
         ((v >> 8) & 16u);
}

__device__ __forceinline__ int bin_of(float cx, float cy, float cz) {
  int xq = (int)((cx + 1.0f) * 16.0f);
  int yq = (int)((cy + 1.0f) * 16.0f);
  int zq = (int)((cz + 1.0f) * 16.0f);
  xq = xq < 0 ? 0 : (xq > 31 ? 31 : xq);
  yq = yq < 0 ? 0 : (yq > 31 ? 31 : yq);
  zq = zq < 0 ? 0 : (zq > 31 ? 31 : zq);
  return (int)(spread3((unsigned)xq) | (spread3((unsigned)yq) << 1) |
               (spread3((unsigned)zq) << 2));
}

// ---------------------------------------------------------------------------
// Zero the bin counters (replaces hipMemsetAsync -> no rocclr fill in graph)
// ---------------------------------------------------------------------------
__global__ __launch_bounds__(1024) void zero_counts(int* __restrict__ counts) {
  counts[blockIdx.x * 1024 + threadIdx.x] = 0;
}

// ---------------------------------------------------------------------------
// Fused: transpose (C,H,W) fp32 -> (H*W,C) fp16*1024 for all 3 scales
// (blocks 0..4031) + bin_count (blocks 4032..5985). One launch.
// ---------------------------------------------------------------------------
__global__ __launch_bounds__(256) void fused_transpose_count(
    const float* __restrict__ coords, const float* __restrict__ px0,
    const float* __restrict__ py0, const float* __restrict__ pz0,
    const float* __restrict__ px1, const float* __restrict__ py1,
    const float* __restrict__ pz1, const float* __restrict__ px2,
    const float* __restrict__ py2, const float* __restrict__ pz2,
    __half* __restrict__ tp, int* __restrict__ counts) {
  const int bid = blockIdx.x;
  if (bid >= 4032) {  // bin_count part
    const int pt = (bid - 4032) * 256 + (int)threadIdx.x;
    if (pt >= NPTS) return;
    const int b =
        bin_of(coords[pt * 3], coords[pt * 3 + 1], coords[pt * 3 + 2]);
    atomicAdd(&counts[b], 1);
    return;
  }
  __shared__ float lds[64][65];
  int p, blk, HW;
  size_t base;
  const float* src;
  if (bid < 3072) {
    p = bid >> 10;
    blk = bid & 1023;
    HW = 65536;
    base = 0;
    src = (p == 0) ? px0 : ((p == 1) ? py0 : pz0);
  } else if (bid < 3840) {
    const int q = bid - 3072;
    p = q >> 8;
    blk = q & 255;
    HW = 16384;
    base = 12582912;
    src = (p == 0) ? px1 : ((p == 1) ? py1 : pz1);
  } else {
    const int q = bid - 3840;
    p = q >> 6;
    blk = q & 63;
    HW = 4096;
    base = 15728640;
    src = (p == 0) ? px2 : ((p == 1) ? py2 : pz2);
  }
  __half* out = tp + base + (size_t)p * (size_t)HW * 64;
  const int pixBase = blk * 64;
  const int tid = threadIdx.x;
  const int lane = tid & 63;
  const int quad = tid >> 6;
#pragma unroll
  for (int k = 0; k < 16; ++k) {
    const int c = k * 4 + quad;
    lds[c][lane] = src[(size_t)c * HW + pixBase + lane];
  }
  __syncthreads();
#pragma unroll
  for (int k = 0; k < 16; ++k) {
    const int pp = k * 4 + quad;
    out[(size_t)(pixBase + pp) * 64 + lane] =
        __float2half(lds[lane][pp] * PLANE_SCALE);
  }
}

__global__ __launch_bounds__(1024) void bin_scan(
    const int* __restrict__ counts, int* __restrict__ cursor) {
  __shared__ int lds[1024];
  const int t = threadIdx.x;
  const int base = t * 32;
  int s = 0;
#pragma unroll
  for (int i = 0; i < 32; ++i) s += counts[base + i];
  lds[t] = s;
  __syncthreads();
  int own = s;
  for (int off = 1; off < 1024; off <<= 1) {
    int v = (t >= off) ? lds[t - off] : 0;
    __syncthreads();
    lds[t] += v;
    __syncthreads();
  }
  int run = lds[t] - own;
#pragma unroll
  for (int i = 0; i < 32; ++i) {
    cursor[base + i] = run;
    run += counts[base + i];
  }
}

// ---------------------------------------------------------------------------
// Scatter fused with weight precompute. Per point, per scale, 32-B record:
// {wx01, wx23, wy01, wy23, wz01, wz23, relx*4|rely*4<<8|relz<<16, pt}
// Merge factors: scale0 m=4 (2x2x1), scales 1-2 m=16 (4x2x2 in x,y,z).
// Window rows: XY 12 (rel_y<=8), YZ 8 (rel_z<=4), XZ 8; cols 16 (rel_x<=12).
// ---------------------------------------------------------------------------
__global__ __launch_bounds__(256) void bin_scatter_prep(
    const float* __restrict__ coords, int* __restrict__ cursor,
    uint4* __restrict__ wrec) {
  const int pt = blockIdx.x * 256 + threadIdx.x;
  if (pt >= NPTS) return;
  const float x = coords[pt * 3], y = coords[pt * 3 + 1],
              z = coords[pt * 3 + 2];
  const int b = bin_of(x, y, z);
  const int pos = atomicAdd(&cursor[b], 1);

  const float vin[3] = {x, y, z};

#pragma unroll
  for (int s = 0; s < 3; ++s) {
    const int W = (s == 0) ? 256 : ((s == 1) ? 128 : 64);
    const float hw = 0.5f * (float)(W - 1);
    const int msk = (s == 0) ? 3 : 15;
    const int bm = b & ~msk;
    const int q0[3] = {(int)compact3((unsigned)bm),
                       (int)compact3((unsigned)bm >> 1),
                       (int)compact3((unsigned)bm >> 2)};
    uint wp[6];
    int rel[3];
#pragma unroll
    for (int a = 0; a < 3; ++a) {
      const float c = (vin[a] + 1.0f) * 0.5f;
      const float gx = (c + 1.0f) * 0.5f * (float)(W - 1);
      const float x0f = floorf(gx);
      float w[4];
      cubic_w(gx - x0f, w);
      const int fb = (int)floorf((1.0f + (float)q0[a] * 0.03125f) * hw);
      int r = (int)x0f - fb;
      const int rmax = (a == 0) ? 12 : ((a == 1) ? 8 : 4);
      r = r < 0 ? 0 : (r > rmax ? rmax : r);
      rel[a] = r;
      const __half2 lo = __halves2half2(__float2half(w[0]), __float2half(w[1]));
      const __half2 hi = __halves2half2(__float2half(w[2]), __float2half(w[3]));
      wp[a * 2] = *(const uint*)&lo;
      wp[a * 2 + 1] = *(const uint*)&hi;
    }
    uint4* dst = wrec + ((size_t)s * NPTS + pos) * 2;
    dst[0] = make_uint4(wp[0], wp[1], wp[2], wp[3]);
    dst[1] = make_uint4(
        wp[4], wp[5],
        (uint)(rel[0] * 4) | ((uint)(rel[1] * 4) << 8) | ((uint)rel[2] << 16),
        (uint)pt);
  }
}

// ---------------------------------------------------------------------------
// Superbin sampling: block per (superbin, scale, ch-half). 32 ch per block.
// LDS: 28 rows (XY 12y, YZ 8z, XZ 8z) x 16 cols x 4 cg uint4 = 28 KB, linear.
// Per-scale merge: scale0 m=4 -> 8192 superbins; scales 1-2 m=16 -> 2048.
// 8 lanes/point; lane i reads slots base+i and base+8+i (row-covering).
// ---------------------------------------------------------------------------
__global__ __launch_bounds__(256, 5) void sample_super(
    const uint4* __restrict__ wrec, const ushort* __restrict__ tp,
    const int* __restrict__ endc, float* __restrict__ out) {
  __shared__ uint4 win[1792];  // 28 rows x 64 uint4 = 28 KB

  const int s = blockIdx.y;
  const int NSUP = (s == 0) ? 8192 : 2048;
  const int m = (s == 0) ? 4 : 16;
  const int orig = blockIdx.x;
  if (orig >= NSUP) return;
  const int sb = (orig & 7) * (NSUP / 8) + (orig >> 3);
  const int b0 = sb * m;
  const int start = (b0 == 0) ? 0 : endc[b0 - 1];
  const int end = endc[b0 + m - 1];
  if (start >= end) return;

  const int h = blockIdx.z;  // channel half: 0 or 1
  const int W = (s == 0) ? 256 : ((s == 1) ? 128 : 64);
  const size_t sbase = (s == 0) ? 0 : ((s == 1) ? 12582912 : 15728640);
  const size_t psz = (size_t)W * W * 64;
  const float hw = 0.5f * (float)(W - 1);

  // b0 is a multiple of m -> merged low bits of qx/qy/qz are already zero
  const int qx0 = (int)compact3((unsigned)b0);
  const int qy0 = (int)compact3((unsigned)b0 >> 1);
  const int qz0 = (int)compact3((unsigned)b0 >> 2);
  const int wbx = (int)floorf((1.0f + (float)qx0 * 0.03125f) * hw) - 1;
  const int wby = (int)floorf((1.0f + (float)qy0 * 0.03125f) * hw) - 1;
  const int wbz = (int)floorf((1.0f + (float)qz0 * 0.03125f) * hw) - 1;

  const char* tpb = (const char*)(tp + sbase) + h * 64;  // 32-ch half
  const int tid = threadIdx.x;
  const int wave = tid >> 6;
  const int lane = tid & 63;
  const int px = lane >> 2;  // 0..15 pixel within row
  const int cgl = lane & 3;  // 0..3 channel group
#pragma unroll
  for (int k = 0; k < 7; ++k) {
    const int row = k * 4 + wave;  // 0..27
    int p, grow, cb;
    if (row < 12) {  // XY rows (y)
      p = 0;
      grow = wby + row;
      cb = wbx;
    } else if (row < 20) {  // YZ rows (z)
      p = 1;
      grow = wbz + row - 12;
      cb = wby;
    } else {  // XZ rows (z)
      p = 2;
      grow = wbz + row - 20;
      cb = wbx;
    }
    grow = grow < 0 ? 0 : (grow > W - 1 ? W - 1 : grow);
    int gcol = cb + px;
    gcol = gcol < 0 ? 0 : (gcol > W - 1 ? W - 1 : gcol);
    const char* src = tpb + (size_t)p * psz * 2 +
                      ((size_t)grow * W + gcol) * 128 + cgl * 16;
#if __has_builtin(__builtin_amdgcn_global_load_lds)
    __builtin_amdgcn_global_load_lds((const uint*)src,
                                     (uint*)&win[row * 64], 16, 0, 0);
#else
    win[row * 64 + lane] = *reinterpret_cast<const uint4*>(src);
#endif
  }
  __syncthreads();

  const int lanegrp = tid >> 3;  // 32 point slots per block iteration
  const int i8 = tid & 7;        // lane's uint4 slot within point segment
  const int cg = tid & 3;        // channel group within half
  const int colpair = (tid >> 2) & 1;  // cols {0,2} or {1,3}

  for (int i0 = start; i0 < end; i0 += 32) {
    const int slot = i0 + lanegrp;
    if (slot >= end) break;
    const uint4 r0 = wrec[((size_t)s * NPTS + slot) * 2];
    const uint4 r1 = wrec[((size_t)s * NPTS + slot) * 2 + 1];
    const int pt = (int)r1.w;
    const int relx4 = (int)(r1.z & 255u);         // rel_x * 4
    const int rely4 = (int)((r1.z >> 8) & 255u);  // rel_y * 4
    const int relz = (int)((r1.z >> 16) & 255u);
    const int rely = rely4 >> 2;

    // broadcast weights
    const __half2 hx01 = *(const __half2*)&r0.x;
    const __half2 hx23 = *(const __half2*)&r0.y;
    const __half2 hy01 = *(const __half2*)&r0.z;
    const __half2 hy23 = *(const __half2*)&r0.w;
    const __half2 hz01 = *(const __half2*)&r1.x;
    const __half2 hz23 = *(const __half2*)&r1.y;
    __half2 wyb[4], wzb[4];
    wyb[0] = __half2half2(__low2half(hy01));
    wyb[1] = __half2half2(__high2half(hy01));
    wyb[2] = __half2half2(__low2half(hy23));
    wyb[3] = __half2half2(__high2half(hy23));
    wzb[0] = __half2half2(__low2half(hz01));
    wzb[1] = __half2half2(__high2half(hz01));
    wzb[2] = __half2half2(__low2half(hz23));
    wzb[3] = __half2half2(__high2half(hz23));
    // per-lane column weights: cols {colpair, colpair+2}
    const __half2 cxA =
        __half2half2(colpair ? __high2half(hx01) : __low2half(hx01));
    const __half2 cxB =
        __half2half2(colpair ? __high2half(hx23) : __low2half(hx23));
    const __half2 cyA =
        __half2half2(colpair ? __high2half(hy01) : __low2half(hy01));
    const __half2 cyB =
        __half2half2(colpair ? __high2half(hy23) : __low2half(hy23));

    // LDS bases (uint4 units); vA = base + j*64, vB = +8
    const int bXY = rely * 64 + relx4 + i8;
    const int bYZ = 768 + relz * 64 + rely4 + i8;   // 12*64
    const int bXZ = 1280 + relz * 64 + relx4 + i8;  // 20*64

    __half2 acc0 = __float2half2_rn(0.0f), acc1 = acc0, acc2 = acc0,
            acc3 = acc0;

#define PLANE(BASE, CWA, CWB, RW)                                   \
  _Pragma("unroll") for (int j = 0; j < 4; ++j) {                   \
    const __half2 mA = __hmul2(CWA, RW[j]);                         \
    const __half2 mB = __hmul2(CWB, RW[j]);                         \
    const uint4 vA = win[(BASE) + j * 64];                          \
    const uint4 vB = win[(BASE) + j * 64 + 8];                      \
    acc0 = __hfma2(mA, *(const __half2*)&vA.x, acc0);               \
    acc1 = __hfma2(mA, *(const __half2*)&vA.y, acc1);               \
    acc2 = __hfma2(mA, *(const __half2*)&vA.z, acc2);               \
    acc3 = __hfma2(mA, *(const __half2*)&vA.w, acc3);               \
    acc0 = __hfma2(mB, *(const __half2*)&vB.x, acc0);               \
    acc1 = __hfma2(mB, *(const __half2*)&vB.y, acc1);               \
    acc2 = __hfma2(mB, *(const __half2*)&vB.z, acc2);               \
    acc3 = __hfma2(mB, *(const __half2*)&vB.w, acc3);               \
  }

    PLANE(bXY, cxA, cxB, wyb);  // XY: row=y, col=x
    PLANE(bYZ, cyA, cyB, wzb);  // YZ: row=z, col=y
    PLANE(bXZ, cxA, cxB, wzb);  // XZ: row=z, col=x
#undef PLANE

    // butterfly over the colpair bit (tid^4): cols {0,2}+{1,3} = all 4
    {
      uint u0 = *(const uint*)&acc0, u1 = *(const uint*)&acc1,
           u2 = *(const uint*)&acc2, u3 = *(const uint*)&acc3;
      const uint p0 = __shfl_xor((int)u0, 4, 64);
      const uint p1 = __shfl_xor((int)u1, 4, 64);
      const uint p2 = __shfl_xor((int)u2, 4, 64);
      const uint p3 = __shfl_xor((int)u3, 4, 64);
      acc0 = __hadd2(acc0, *(const __half2*)&p0);
      acc1 = __hadd2(acc1, *(const __half2*)&p1);
      acc2 = __hadd2(acc2, *(const __half2*)&p2);
      acc3 = __hadd2(acc3, *(const __half2*)&p3);
    }

    // lane writes 4 of its 8 channels, selected by colpair -> 128 B/point
    const __half2 o0 = colpair ? acc2 : acc0;
    const __half2 o1 = colpair ? acc3 : acc1;
    const float2 f0 = __half22float2(o0);
    const float2 f1 = __half22float2(o1);
    *reinterpret_cast<float4*>(out + (size_t)pt * 192 + s * 64 + h * 32 +
                               cg * 8 + colpair * 4) =
        make_float4(f0.x * INV_PLANE_SCALE, f0.y * INV_PLANE_SCALE,
                    f1.x * INV_PLANE_SCALE, f1.y * INV_PLANE_SCALE);
  }
}

// ---------------------------------------------------------------------------
// Fallback: fp32 direct from (C,H,W) if workspace too small.
// ---------------------------------------------------------------------------
__device__ __forceinline__ void sample_acc_chw(const float* __restrict__ plane,
                                               int W, float gx, float gy,
                                               int cg, float4& acc) {
  const float x = (gx + 1.0f) * 0.5f * (float)(W - 1);
  const float y = (gy + 1.0f) * 0.5f * (float)(W - 1);
  const float x0f = floorf(x), y0f = floorf(y);
  float wx[4], wy[4];
  cubic_w(x - x0f, wx);
  cubic_w(y - y0f, wy);
  const int x0 = (int)x0f, y0 = (int)y0f;
  int ix[4], iy[4];
#pragma unroll
  for (int i = 0; i < 4; ++i) {
    int xi = x0 - 1 + i;
    ix[i] = xi < 0 ? 0 : (xi > W - 1 ? W - 1 : xi);
    int yi = y0 - 1 + i;
    iy[i] = yi < 0 ? 0 : (yi > W - 1 ? W - 1 : yi);
  }
  const size_t HW = (size_t)W * W;
  float r[4] = {acc.x, acc.y, acc.z, acc.w};
#pragma unroll
  for (int cc = 0; cc < 4; ++cc) {
    const float* pc = plane + (size_t)(cg * 4 + cc) * HW;
    float a = 0.f;
#pragma unroll
    for (int j = 0; j < 4; ++j) {
      const float* rb = pc + (size_t)iy[j] * W;
      float row = 0.f;
#pragma unroll
      for (int i = 0; i < 4; ++i) row += wx[i] * rb[ix[i]];
      a += wy[j] * row;
    }
    r[cc] += a;
  }
  acc = make_float4(r[0], r[1], r[2], r[3]);
}

__global__ __launch_bounds__(256) void sample_fallback(
    const float* __restrict__ coords, const float* __restrict__ px0,
    const float* __restrict__ py0, const float* __restrict__ pz0,
    const float* __restrict__ px1, const float* __restrict__ py1,
    const float* __restrict__ pz1, const float* __restrict__ px2,
    const float* __restrict__ py2, const float* __restrict__ pz2,
    float* __restrict__ out) {
  const int t = blockIdx.x * 256 + threadIdx.x;
  const int pt = t >> 4;
  const int cg = t & 15;
  if (pt >= NPTS) return;
  const float cx = (coords[pt * 3 + 0] + 1.0f) * 0.5f;
  const float cy = (coords[pt * 3 + 1] + 1.0f) * 0.5f;
  const float cz = (coords[pt * 3 + 2] + 1.0f) * 0.5f;
  const float* xs[3] = {px0, px1, px2};
  const float* ys[3] = {py0, py1, py2};
  const float* zs[3] = {pz0, pz1, pz2};
  const int sw[3] = {256, 128, 64};
  float* optr = out + (size_t)pt * 192 + cg * 4;
#pragma unroll
  for (int s = 0; s < 3; ++s) {
    const int W = sw[s];
    float4 acc = make_float4(0.f, 0.f, 0.f, 0.f);
    sample_acc_chw(xs[s], W, cx, cy, cg, acc);
    sample_acc_chw(ys[s], W, cy, cz, cg, acc);
    sample_acc_chw(zs[s], W, cx, cz, cg, acc);
    *reinterpret_cast<float4*>(optr + s * 64) = acc;
  }
}

// ---------------------------------------------------------------------------
extern "C" void kernel_launch(void* const* d_in, const int* in_sizes, int n_in,
                              void* d_out, int out_size, void* d_ws,
                              size_t ws_size, hipStream_t stream) {
  const float* coords = (const float*)d_in[0];
  const float* px0 = (const float*)d_in[1];
  const float* py0 = (const float*)d_in[2];
  const float* pz0 = (const float*)d_in[3];
  const float* px1 = (const float*)d_in[4];
  const float* py1 = (const float*)d_in[5];
  const float* pz1 = (const float*)d_in[6];
  const float* px2 = (const float*)d_in[7];
  const float* py2 = (const float*)d_in[8];
  const float* pz2 = (const float*)d_in[9];
  float* out = (float*)d_out;

  // ws layout (bytes): f16 planes, counts, end-cursor, weight records
  const size_t TP_BYTES = 33030144;
  const size_t CNT_OFF = TP_BYTES;           // 131072 B
  const size_t CUR_OFF = CNT_OFF + 131072;   // 131072 B
  const size_t REC_OFF = CUR_OFF + 131072;   // 48,000,000 B
  const size_t NEEDED = REC_OFF + (size_t)NPTS * 3 * 32;

  if (ws_size >= NEEDED) {
    __half* tp = (__half*)d_ws;
    int* counts = (int*)((char*)d_ws + CNT_OFF);
    int* cursor = (int*)((char*)d_ws + CUR_OFF);
    uint4* wrec = (uint4*)((char*)d_ws + REC_OFF);

    zero_counts<<<NBINS / 1024, 1024, 0, stream>>>(counts);

    const int pblocks = (NPTS + 255) / 256;  // 1954
    fused_transpose_count<<<4032 + pblocks, 256, 0, stream>>>(
        coords, px0, py0, pz0, px1, py1, pz1, px2, py2, pz2, tp, counts);

    bin_scan<<<1, 1024, 0, stream>>>(counts, cursor);
    bin_scatter_prep<<<pblocks, 256, 0, stream>>>(coords, cursor, wrec);
    // cursor[b] now == end offset of bin b

    sample_super<<<dim3(8192, 3, 2), 256, 0, stream>>>(
        wrec, (const ushort*)tp, cursor, out);
  } else {
    const int sample_blocks = (NPTS * 16 + 255) / 256;
    sample_fallback<<<sample_blocks, 256, 0, stream>>>(
        coords, px0, py0, pz0, px1, py1, pz1, px2, py2, pz2, out);
  }
}